// Round 5
// baseline (180.419 us; speedup 1.0000x reference)
//
#include <hip/hip_runtime.h>
#include <cmath>

#define S_TOT 4096
#define CIN   256
#define HID   512
#define NHEAD 8
#define DIMH  64

typedef __attribute__((ext_vector_type(8))) short bf16x8;
typedef __attribute__((ext_vector_type(4))) float f32x4;
typedef __attribute__((address_space(1))) const void gv_t;
typedef __attribute__((address_space(3))) void lv_t;

__device__ __forceinline__ ushort f2bf(float f) {
    union { float f; unsigned u; } v; v.f = f;
    unsigned r = (v.u + 0x7FFFu + ((v.u >> 16) & 1u)) >> 16;
    return (ushort)r;
}

__device__ __forceinline__ float exp2_fast(float x) {
    float r; asm("v_exp_f32 %0, %1" : "=v"(r) : "v"(x)); return r;
}

__device__ __forceinline__ unsigned cvt_pk_bf16(float lo, float hi) {
    unsigned r; asm("v_cvt_pk_bf16_f32 %0, %1, %2" : "=v"(r) : "v"(lo), "v"(hi)); return r;
}

// 0.125 (1/sqrt(64)) * log2(e): folds softmax base-2 conversion into Q.
#define QSCALE 0.18033688011112042f

// ---------------------------------------------------------------------------
// Elementwise fp32 -> bf16 cast (vectorized), n % 4 == 0
// ---------------------------------------------------------------------------
__global__ __launch_bounds__(256)
void cast_f32_bf16(const float* __restrict__ in, ushort* __restrict__ out, long n) {
    long i = ((long)blockIdx.x * 256 + threadIdx.x) * 4;
    if (i < n) {
        float4 v = *(const float4*)&in[i];
        ushort4 p;
        p.x = f2bf(v.x); p.y = f2bf(v.y); p.z = f2bf(v.z); p.w = f2bf(v.w);
        *(ushort4*)&out[i] = p;
    }
}

// ---------------------------------------------------------------------------
// Transpose-cast: x [b][256][4096] fp32 -> xt [b][4096][256] bf16
// ---------------------------------------------------------------------------
__global__ __launch_bounds__(256)
void transpose_cast_x(const float* __restrict__ x, ushort* __restrict__ xt) {
    __shared__ float tb[64][65];
    const int t = threadIdx.x;
    const int s0 = blockIdx.x * 64, c0 = blockIdx.y * 64;
    const long xb = (long)blockIdx.z * CIN * S_TOT;
    #pragma unroll
    for (int i = 0; i < 16; ++i) {
        int idx = t + i * 256;
        int c = idx >> 6, s = idx & 63;
        tb[c][s] = x[xb + (long)(c0 + c) * S_TOT + s0 + s];
    }
    __syncthreads();
    const long ob = (long)blockIdx.z * S_TOT * CIN;
    const int s = t >> 2, cq = (t & 3) * 16;
    #pragma unroll
    for (int j = 0; j < 4; ++j) {
        ushort4 pk;
        pk.x = f2bf(tb[cq + j * 4 + 0][s]);
        pk.y = f2bf(tb[cq + j * 4 + 1][s]);
        pk.z = f2bf(tb[cq + j * 4 + 2][s]);
        pk.w = f2bf(tb[cq + j * 4 + 3][s]);
        *(ushort4*)&xt[ob + (long)(s0 + s) * CIN + c0 + cq + j * 4] = pk;
    }
}

// ---------------------------------------------------------------------------
// bf16 MFMA GEMM: D[ar][br] = sum_k A[ar][k] * B[br][k]   (both K-contiguous)
// MODE 0: A=xt, B=w_qkv[0:1024] -> q (pre-scaled by QSCALE) / k, [bh][s][64]
// MODE 1: A=w_qkv[1024:1536], B=xt -> v [bh][d][s_perm]  (key order permuted
//         within each 64-key tile so attention's register-resident P matches:
//         j -> 32*(j>>5) + 8*((j>>2)&3) + 4*((j>>4)&1) + (j&3))
// MODE 2: A=w_out, B=attn-bf16 -> out [b][o][s] fp32 + bias
// ---------------------------------------------------------------------------
template<int MODE>
__global__ __launch_bounds__(256)
void gemm_mfma_kernel(const ushort* __restrict__ Ag, const ushort* __restrict__ Bg,
                      void* __restrict__ outp, const float* __restrict__ bias,
                      int Kdim, long strideA, long strideB) {
    __shared__ __attribute__((aligned(16))) ushort Abuf[128 * 64];
    __shared__ __attribute__((aligned(16))) ushort Bbuf[128 * 64];
    const int t = threadIdx.x, lane = t & 63;
    const int l15 = lane & 15, g = lane >> 4;
    const int wid = t >> 6, wr = wid >> 1, wc = wid & 1;
    const int bz = blockIdx.z;
    const int am0 = blockIdx.y * 128, bn0 = blockIdx.x * 128;
    Ag += (long)bz * strideA;
    Bg += (long)bz * strideB;

    f32x4 acc[4][4];
    #pragma unroll
    for (int i = 0; i < 4; ++i)
        #pragma unroll
        for (int j = 0; j < 4; ++j)
            acc[i][j] = (f32x4){0.f, 0.f, 0.f, 0.f};

    for (int k0 = 0; k0 < Kdim; k0 += 64) {
        __syncthreads();
        #pragma unroll
        for (int i = 0; i < 4; ++i) {
            const int chunk = t + i * 256;
            const int row = chunk >> 3, sl = chunk & 7;
            const ushort* srcA = Ag + (long)(am0 + row) * Kdim + k0 + ((sl ^ (row & 7)) << 3);
            __builtin_amdgcn_global_load_lds((gv_t*)srcA,
                (lv_t*)((char*)Abuf + (i * 256 + (t & ~63)) * 16), 16, 0, 0);
            const ushort* srcB = Bg + (long)(bn0 + row) * Kdim + k0 + ((sl ^ (row & 7)) << 3);
            __builtin_amdgcn_global_load_lds((gv_t*)srcB,
                (lv_t*)((char*)Bbuf + (i * 256 + (t & ~63)) * 16), 16, 0, 0);
        }
        asm volatile("s_waitcnt vmcnt(0)" ::: "memory");
        __syncthreads();

        bf16x8 bfr[4][2];
        #pragma unroll
        for (int fn = 0; fn < 4; ++fn) {
            const int row = wc * 64 + fn * 16 + l15;
            #pragma unroll
            for (int hf = 0; hf < 2; ++hf)
                bfr[fn][hf] = *(const bf16x8*)((const char*)Bbuf + row * 128
                                + (((hf * 4 + g) ^ (row & 7)) << 4));
        }
        #pragma unroll
        for (int fm = 0; fm < 4; ++fm) {
            const int row = wr * 64 + fm * 16 + l15;
            const bf16x8 a0 = *(const bf16x8*)((const char*)Abuf + row * 128
                                + (((g) ^ (row & 7)) << 4));
            const bf16x8 a1 = *(const bf16x8*)((const char*)Abuf + row * 128
                                + (((4 + g) ^ (row & 7)) << 4));
            #pragma unroll
            for (int fn = 0; fn < 4; ++fn) {
                acc[fm][fn] = __builtin_amdgcn_mfma_f32_16x16x32_bf16(a0, bfr[fn][0], acc[fm][fn], 0, 0, 0);
                acc[fm][fn] = __builtin_amdgcn_mfma_f32_16x16x32_bf16(a1, bfr[fn][1], acc[fm][fn], 0, 0, 0);
            }
        }
    }

    #pragma unroll
    for (int fm = 0; fm < 4; ++fm)
        #pragma unroll
        for (int fn = 0; fn < 4; ++fn)
            #pragma unroll
            for (int r = 0; r < 4; ++r) {
                const int ar = am0 + wr * 64 + fm * 16 + g * 4 + r;
                const int bc = bn0 + wc * 64 + fn * 16 + l15;
                if (MODE == 0) {
                    const int which = bc >> 9, h = (bc >> 6) & 7, d = bc & 63;
                    const float scl = (which == 0) ? QSCALE : 1.0f;
                    ushort* O = (ushort*)outp;
                    O[(long)which * 4194304 + (((long)(bz * NHEAD + h)) * S_TOT + ar) * DIMH + d]
                        = f2bf(acc[fm][fn][r] * scl);
                } else if (MODE == 1) {
                    const int h = ar >> 6, d = ar & 63;
                    const int j = bc & 63;
                    const int pj = ((j >> 5) << 5) | (((j >> 2) & 3) << 3)
                                 | (((j >> 4) & 1) << 2) | (j & 3);
                    const int pc = (bc & ~63) | pj;
                    ushort* O = (ushort*)outp;
                    O[(((long)(bz * NHEAD + h)) * DIMH + d) * S_TOT + pc] = f2bf(acc[fm][fn][r]);
                } else {
                    float* O = (float*)outp;
                    O[((long)bz * CIN + ar) * S_TOT + bc] = acc[fm][fn][r] + bias[ar];
                }
            }
}

// ---------------------------------------------------------------------------
// Flash attention, swapped-QK, P fully in registers:
// lane (g,l15) owns q=l15, keys 16kb+4g+r after QK^T; the PV A-fragment
// needs q=l15, k-slots g*8+j on the SAME lane -> no P movement at all.
// Key->k-slot mismatch is absorbed into V's global key permutation (MODE 1).
// Lazy reductions: defer-max votes on per-lane max (reduce only on trigger);
// lrun kept as per-lane partial, reduced once in epilogue.
// ---------------------------------------------------------------------------
__global__ __launch_bounds__(256)
void attn_mfma_kernel(const ushort* __restrict__ qg, const ushort* __restrict__ kg,
                      const ushort* __restrict__ vg, ushort* __restrict__ aout) {
    __shared__ __attribute__((aligned(16))) ushort kbuf[2][64 * 64];
    __shared__ __attribute__((aligned(16))) ushort vbuf[2][64 * 64];

    const int t = threadIdx.x;
    const int lane = t & 63, wid = t >> 6;
    const int l15 = lane & 15, g = lane >> 4;
    const int h = blockIdx.y, b = blockIdx.z;
    const int bh = b * NHEAD + h;
    const int qrow0 = blockIdx.x * 64 + wid * 16;

    // Q B-fragment: row = q = l15, k-slot g (already scaled by QSCALE*log2e)
    const ushort* qp = qg + ((long)bh * S_TOT + qrow0 + l15) * DIMH + g * 8;
    const bf16x8 qf0 = *(const bf16x8*)qp;
    const bf16x8 qf1 = *(const bf16x8*)(qp + 32);

    f32x4 oacc[4];
    #pragma unroll
    for (int f = 0; f < 4; ++f) oacc[f] = (f32x4){0.f, 0.f, 0.f, 0.f};
    float mrun = -3e38f, lrun = 0.f;   // per-lane (q = l15, this lane's keys)

    const long kg_base = (long)bh * S_TOT * DIMH;
    const long vg_base = (long)bh * DIMH * S_TOT;
    const int sl = lane & 7, sr = lane >> 3;
    const int swz = sl ^ sr;

    auto STAGE = [&](int buf, long key0) {
        char* kdst = (char*)(&kbuf[buf][0]) + wid * 1024;
        char* vdst = (char*)(&vbuf[buf][0]) + wid * 1024;
        #pragma unroll
        for (int c = 0; c < 2; ++c) {
            const int row = (wid + c * 4) * 8 + sr;
            const char* srcK = (const char*)(kg + kg_base + (key0 + row) * DIMH) + swz * 16;
            __builtin_amdgcn_global_load_lds((gv_t*)srcK, (lv_t*)(kdst + c * 4096), 16, 0, 0);
            const char* srcV = (const char*)(vg + vg_base + (long)row * S_TOT + key0) + swz * 16;
            __builtin_amdgcn_global_load_lds((gv_t*)srcV, (lv_t*)(vdst + c * 4096), 16, 0, 0);
        }
    };

    STAGE(0, 0);
    asm volatile("s_waitcnt vmcnt(0)" ::: "memory");
    __syncthreads();

    for (int kt0 = 0; kt0 < S_TOT / 64; ++kt0) {
        const int cur = kt0 & 1;
        if (kt0 + 1 < S_TOT / 64) STAGE(cur ^ 1, (long)(kt0 + 1) * 64);

        const char* kb_ = (const char*)(&kbuf[cur][0]);
        const char* vb_ = (const char*)(&vbuf[cur][0]);

        // --- S^T = K Q^T (lane: q=l15, key = kb*16 + g*4 + r) ---
        f32x4 sacc[4];
        __builtin_amdgcn_s_setprio(1);
        #pragma unroll
        for (int kb = 0; kb < 4; ++kb) {
            const int krow = kb * 16 + l15, ks = krow & 7;
            const bf16x8 kf0 = *(const bf16x8*)(kb_ + krow * 128 + ((g ^ ks) << 4));
            const bf16x8 kf1 = *(const bf16x8*)(kb_ + krow * 128 + (((4 + g) ^ ks) << 4));
            sacc[kb] = (f32x4){0.f, 0.f, 0.f, 0.f};
            sacc[kb] = __builtin_amdgcn_mfma_f32_16x16x32_bf16(kf0, qf0, sacc[kb], 0, 0, 0);
            sacc[kb] = __builtin_amdgcn_mfma_f32_16x16x32_bf16(kf1, qf1, sacc[kb], 0, 0, 0);
        }
        __builtin_amdgcn_s_setprio(0);

        // prefetch V B-fragments into registers (overlaps softmax)
        bf16x8 vfr[2][4];
        #pragma unroll
        for (int ks = 0; ks < 2; ++ks)
            #pragma unroll
            for (int f = 0; f < 4; ++f) {
                const int vrow = f * 16 + l15;
                vfr[ks][f] = *(const bf16x8*)(vb_ + vrow * 128
                                + (((ks * 4 + g) ^ (vrow & 7)) << 4));
            }

        // --- per-lane max, vote, rare full reduce + rescale ---
        float tmax = fmaxf(fmaxf(sacc[0][0], sacc[0][1]), fmaxf(sacc[0][2], sacc[0][3]));
        #pragma unroll
        for (int kb = 1; kb < 4; ++kb)
            tmax = fmaxf(tmax, fmaxf(fmaxf(sacc[kb][0], sacc[kb][1]),
                                     fmaxf(sacc[kb][2], sacc[kb][3])));

        if (__any(tmax > mrun + 8.0f)) {
            float tm = fmaxf(tmax, __shfl_xor(tmax, 16, 64));
            tm = fmaxf(tm, __shfl_xor(tm, 32, 64));
            const float mn = fmaxf(mrun, tm);
            const float al = exp2_fast(mrun - mn);
            lrun *= al;
            #pragma unroll
            for (int r = 0; r < 4; ++r) {
                const float alg = __shfl(al, g * 4 + r, 64);
                #pragma unroll
                for (int f = 0; f < 4; ++f) oacc[f][r] *= alg;
            }
            mrun = mn;
        }

        // --- exp + pack P in registers (keys 16kb+4g+{0..3} -> pw[2kb..]) ---
        unsigned pw[8];
        #pragma unroll
        for (int kb = 0; kb < 4; ++kb) {
            const float p0 = exp2_fast(sacc[kb][0] - mrun);
            const float p1 = exp2_fast(sacc[kb][1] - mrun);
            const float p2 = exp2_fast(sacc[kb][2] - mrun);
            const float p3 = exp2_fast(sacc[kb][3] - mrun);
            lrun += (p0 + p1) + (p2 + p3);
            pw[kb * 2]     = cvt_pk_bf16(p0, p1);
            pw[kb * 2 + 1] = cvt_pk_bf16(p2, p3);
        }

        // --- O += P V (P fragment = register rename; V keys pre-permuted) ---
        __builtin_amdgcn_s_setprio(1);
        #pragma unroll
        for (int ks = 0; ks < 2; ++ks) {
            union { unsigned u[4]; bf16x8 v; } pu;
            pu.u[0] = pw[ks * 4 + 0]; pu.u[1] = pw[ks * 4 + 1];
            pu.u[2] = pw[ks * 4 + 2]; pu.u[3] = pw[ks * 4 + 3];
            #pragma unroll
            for (int f = 0; f < 4; ++f)
                oacc[f] = __builtin_amdgcn_mfma_f32_16x16x32_bf16(pu.v, vfr[ks][f], oacc[f], 0, 0, 0);
        }
        __builtin_amdgcn_s_setprio(0);

        asm volatile("s_waitcnt vmcnt(0)" ::: "memory");
        __syncthreads();
    }

    // epilogue: reduce lrun across the 4 lanes of each q, then normalize
    lrun += __shfl_xor(lrun, 16, 64);
    lrun += __shfl_xor(lrun, 32, 64);
    #pragma unroll
    for (int r = 0; r < 4; ++r) {
        const float inv = 1.0f / __shfl(lrun, g * 4 + r, 64);
        const long srow = (long)b * S_TOT + qrow0 + g * 4 + r;
        #pragma unroll
        for (int f = 0; f < 4; ++f)
            aout[srow * HID + h * 64 + f * 16 + l15] = f2bf(oacc[f][r] * inv);
    }
}

// ---------------------------------------------------------------------------
extern "C" void kernel_launch(void* const* d_in, const int* in_sizes, int n_in,
                              void* d_out, int out_size, void* d_ws, size_t ws_size,
                              hipStream_t stream) {
    const float* x     = (const float*)d_in[0];
    const float* w_qkv = (const float*)d_in[1];
    const float* w_out = (const float*)d_in[2];
    const float* b_out = (const float*)d_in[3];
    float* out = (float*)d_out;

    const long PERQKV = (long)2 * NHEAD * S_TOT * DIMH;
    ushort* qws = (ushort*)d_ws;
    ushort* kws = qws + PERQKV;
    ushort* vws = kws + PERQKV;
    ushort* xt  = vws + PERQKV;
    ushort* wqb = xt + (long)2 * S_TOT * CIN;
    ushort* wob = wqb + (long)3 * HID * CIN;
    ushort* awb = wob + (long)CIN * HID;

    cast_f32_bf16<<<dim3((3 * HID * CIN / 4 + 255) / 256), 256, 0, stream>>>(
        w_qkv, wqb, (long)3 * HID * CIN);
    cast_f32_bf16<<<dim3((CIN * HID / 4 + 255) / 256), 256, 0, stream>>>(
        w_out, wob, (long)CIN * HID);
    transpose_cast_x<<<dim3(S_TOT / 64, CIN / 64, 2), 256, 0, stream>>>(x, xt);

    gemm_mfma_kernel<0><<<dim3(1024 / 128, S_TOT / 128, 2), 256, 0, stream>>>(
        xt, wqb, qws, nullptr, CIN, (long)S_TOT * CIN, 0L);
    gemm_mfma_kernel<1><<<dim3(S_TOT / 128, 512 / 128, 2), 256, 0, stream>>>(
        wqb + (long)1024 * CIN, xt, vws, nullptr, CIN, 0L, (long)S_TOT * CIN);

    attn_mfma_kernel<<<dim3(S_TOT / 64, NHEAD, 2), 256, 0, stream>>>(qws, kws, vws, awb);

    gemm_mfma_kernel<2><<<dim3(S_TOT / 128, CIN / 128, 2), 256, 0, stream>>>(
        wob, awb, out, b_out, HID, 0L, (long)S_TOT * HID);
}

// Round 6
// 135.037 us; speedup vs baseline: 1.3361x; 1.3361x over previous
//
#include <hip/hip_runtime.h>
#include <cmath>

#define S_TOT 4096
#define CIN   256
#define HID   512
#define NHEAD 8
#define DIMH  64

typedef __attribute__((ext_vector_type(8))) short bf16x8;
typedef __attribute__((ext_vector_type(4))) float f32x4;
typedef __attribute__((address_space(1))) const void gv_t;
typedef __attribute__((address_space(3))) void lv_t;

__device__ __forceinline__ ushort f2bf(float f) {
    union { float f; unsigned u; } v; v.f = f;
    unsigned r = (v.u + 0x7FFFu + ((v.u >> 16) & 1u)) >> 16;
    return (ushort)r;
}

__device__ __forceinline__ float exp2_fast(float x) {
    float r; asm("v_exp_f32 %0, %1" : "=v"(r) : "v"(x)); return r;
}

__device__ __forceinline__ unsigned cvt_pk_bf16(float lo, float hi) {
    unsigned r; asm("v_cvt_pk_bf16_f32 %0, %1, %2" : "=v"(r) : "v"(lo), "v"(hi)); return r;
}

// 0.125 (1/sqrt(64)) * log2(e): folds softmax base-2 conversion into Q.
#define QSCALE 0.18033688011112042f

// ---------------------------------------------------------------------------
// Elementwise fp32 -> bf16 cast (vectorized), n % 4 == 0
// ---------------------------------------------------------------------------
__global__ __launch_bounds__(256)
void cast_f32_bf16(const float* __restrict__ in, ushort* __restrict__ out, long n) {
    long i = ((long)blockIdx.x * 256 + threadIdx.x) * 4;
    if (i < n) {
        float4 v = *(const float4*)&in[i];
        ushort4 p;
        p.x = f2bf(v.x); p.y = f2bf(v.y); p.z = f2bf(v.z); p.w = f2bf(v.w);
        *(ushort4*)&out[i] = p;
    }
}

// ---------------------------------------------------------------------------
// Transpose-cast: x [b][256][4096] fp32 -> xt [b][4096][256] bf16
// ---------------------------------------------------------------------------
__global__ __launch_bounds__(256)
void transpose_cast_x(const float* __restrict__ x, ushort* __restrict__ xt) {
    __shared__ float tb[64][65];
    const int t = threadIdx.x;
    const int s0 = blockIdx.x * 64, c0 = blockIdx.y * 64;
    const long xb = (long)blockIdx.z * CIN * S_TOT;
    #pragma unroll
    for (int i = 0; i < 16; ++i) {
        int idx = t + i * 256;
        int c = idx >> 6, s = idx & 63;
        tb[c][s] = x[xb + (long)(c0 + c) * S_TOT + s0 + s];
    }
    __syncthreads();
    const long ob = (long)blockIdx.z * S_TOT * CIN;
    const int s = t >> 2, cq = (t & 3) * 16;
    #pragma unroll
    for (int j = 0; j < 4; ++j) {
        ushort4 pk;
        pk.x = f2bf(tb[cq + j * 4 + 0][s]);
        pk.y = f2bf(tb[cq + j * 4 + 1][s]);
        pk.z = f2bf(tb[cq + j * 4 + 2][s]);
        pk.w = f2bf(tb[cq + j * 4 + 3][s]);
        *(ushort4*)&xt[ob + (long)(s0 + s) * CIN + c0 + cq + j * 4] = pk;
    }
}

// ---------------------------------------------------------------------------
// bf16 MFMA GEMM: D[ar][br] = sum_k A[ar][k] * B[br][k]   (both K-contiguous)
// MODE 0: A=xt, B=w_qkv[0:1024] -> q (pre-scaled by QSCALE) / k, [bh][s][64]
// MODE 1: A=w_qkv[1024:1536], B=xt -> v [bh][d][s_perm]  (key order permuted
//         within each 64-key tile so attention's register-resident P matches:
//         j -> 32*(j>>5) + 8*((j>>2)&3) + 4*((j>>4)&1) + (j&3))
// MODE 2: A=w_out, B=attn-bf16 -> out [b][o][s] fp32 + bias
// ---------------------------------------------------------------------------
template<int MODE>
__global__ __launch_bounds__(256)
void gemm_mfma_kernel(const ushort* __restrict__ Ag, const ushort* __restrict__ Bg,
                      void* __restrict__ outp, const float* __restrict__ bias,
                      int Kdim, long strideA, long strideB) {
    __shared__ __attribute__((aligned(16))) ushort Abuf[128 * 64];
    __shared__ __attribute__((aligned(16))) ushort Bbuf[128 * 64];
    const int t = threadIdx.x, lane = t & 63;
    const int l15 = lane & 15, g = lane >> 4;
    const int wid = t >> 6, wr = wid >> 1, wc = wid & 1;
    const int bz = blockIdx.z;
    const int am0 = blockIdx.y * 128, bn0 = blockIdx.x * 128;
    Ag += (long)bz * strideA;
    Bg += (long)bz * strideB;

    f32x4 acc[4][4];
    #pragma unroll
    for (int i = 0; i < 4; ++i)
        #pragma unroll
        for (int j = 0; j < 4; ++j)
            acc[i][j] = (f32x4){0.f, 0.f, 0.f, 0.f};

    for (int k0 = 0; k0 < Kdim; k0 += 64) {
        __syncthreads();
        #pragma unroll
        for (int i = 0; i < 4; ++i) {
            const int chunk = t + i * 256;
            const int row = chunk >> 3, sl = chunk & 7;
            const ushort* srcA = Ag + (long)(am0 + row) * Kdim + k0 + ((sl ^ (row & 7)) << 3);
            __builtin_amdgcn_global_load_lds((gv_t*)srcA,
                (lv_t*)((char*)Abuf + (i * 256 + (t & ~63)) * 16), 16, 0, 0);
            const ushort* srcB = Bg + (long)(bn0 + row) * Kdim + k0 + ((sl ^ (row & 7)) << 3);
            __builtin_amdgcn_global_load_lds((gv_t*)srcB,
                (lv_t*)((char*)Bbuf + (i * 256 + (t & ~63)) * 16), 16, 0, 0);
        }
        asm volatile("s_waitcnt vmcnt(0)" ::: "memory");
        __syncthreads();

        bf16x8 bfr[4][2];
        #pragma unroll
        for (int fn = 0; fn < 4; ++fn) {
            const int row = wc * 64 + fn * 16 + l15;
            #pragma unroll
            for (int hf = 0; hf < 2; ++hf)
                bfr[fn][hf] = *(const bf16x8*)((const char*)Bbuf + row * 128
                                + (((hf * 4 + g) ^ (row & 7)) << 4));
        }
        #pragma unroll
        for (int fm = 0; fm < 4; ++fm) {
            const int row = wr * 64 + fm * 16 + l15;
            const bf16x8 a0 = *(const bf16x8*)((const char*)Abuf + row * 128
                                + (((g) ^ (row & 7)) << 4));
            const bf16x8 a1 = *(const bf16x8*)((const char*)Abuf + row * 128
                                + (((4 + g) ^ (row & 7)) << 4));
            #pragma unroll
            for (int fn = 0; fn < 4; ++fn) {
                acc[fm][fn] = __builtin_amdgcn_mfma_f32_16x16x32_bf16(a0, bfr[fn][0], acc[fm][fn], 0, 0, 0);
                acc[fm][fn] = __builtin_amdgcn_mfma_f32_16x16x32_bf16(a1, bfr[fn][1], acc[fm][fn], 0, 0, 0);
            }
        }
    }

    #pragma unroll
    for (int fm = 0; fm < 4; ++fm)
        #pragma unroll
        for (int fn = 0; fn < 4; ++fn)
            #pragma unroll
            for (int r = 0; r < 4; ++r) {
                const int ar = am0 + wr * 64 + fm * 16 + g * 4 + r;
                const int bc = bn0 + wc * 64 + fn * 16 + l15;
                if (MODE == 0) {
                    const int which = bc >> 9, h = (bc >> 6) & 7, d = bc & 63;
                    const float scl = (which == 0) ? QSCALE : 1.0f;
                    ushort* O = (ushort*)outp;
                    O[(long)which * 4194304 + (((long)(bz * NHEAD + h)) * S_TOT + ar) * DIMH + d]
                        = f2bf(acc[fm][fn][r] * scl);
                } else if (MODE == 1) {
                    const int h = ar >> 6, d = ar & 63;
                    const int j = bc & 63;
                    const int pj = ((j >> 5) << 5) | (((j >> 2) & 3) << 3)
                                 | (((j >> 4) & 1) << 2) | (j & 3);
                    const int pc = (bc & ~63) | pj;
                    ushort* O = (ushort*)outp;
                    O[(((long)(bz * NHEAD + h)) * DIMH + d) * S_TOT + pc] = f2bf(acc[fm][fn][r]);
                } else {
                    float* O = (float*)outp;
                    O[((long)bz * CIN + ar) * S_TOT + bc] = acc[fm][fn][r] + bias[ar];
                }
            }
}

// ---------------------------------------------------------------------------
// Flash attention, swapped-QK, P fully in registers (round-4 dataflow), now
// 8 waves / 512 threads per block covering 128 q-rows: K/V staged once per
// block per tile (2 global_load_lds per wave), V fragments read from LDS
// inside the PV loop (no register prefetch -> lower VGPR, more waves/SIMD).
// ---------------------------------------------------------------------------
__global__ __launch_bounds__(512)
void attn_mfma_kernel(const ushort* __restrict__ qg, const ushort* __restrict__ kg,
                      const ushort* __restrict__ vg, ushort* __restrict__ aout) {
    __shared__ __attribute__((aligned(16))) ushort kbuf[2][64 * 64];
    __shared__ __attribute__((aligned(16))) ushort vbuf[2][64 * 64];

    const int t = threadIdx.x;
    const int lane = t & 63, wid = t >> 6;          // wid 0..7
    const int l15 = lane & 15, g = lane >> 4;
    const int h = blockIdx.y, b = blockIdx.z;
    const int bh = b * NHEAD + h;
    const int qrow0 = blockIdx.x * 128 + wid * 16;

    // Q B-fragment: row = q = l15, k-slot g (already scaled by QSCALE)
    const ushort* qp = qg + ((long)bh * S_TOT + qrow0 + l15) * DIMH + g * 8;
    const bf16x8 qf0 = *(const bf16x8*)qp;
    const bf16x8 qf1 = *(const bf16x8*)(qp + 32);

    f32x4 oacc[4];
    #pragma unroll
    for (int f = 0; f < 4; ++f) oacc[f] = (f32x4){0.f, 0.f, 0.f, 0.f};
    float mrun = -3e38f, lrun = 0.f;   // per-lane (q = l15, this lane's keys)

    const long kg_base = (long)bh * S_TOT * DIMH;
    const long vg_base = (long)bh * DIMH * S_TOT;
    const int sl = lane & 7, sr = lane >> 3;
    const int swz = sl ^ sr;

    // wave wid stages rows 8*wid .. 8*wid+7 of both K and V tiles (1 KB each)
    auto STAGE = [&](int buf, long key0) {
        const int row = wid * 8 + sr;
        char* kdst = (char*)(&kbuf[buf][0]) + wid * 1024;
        char* vdst = (char*)(&vbuf[buf][0]) + wid * 1024;
        const char* srcK = (const char*)(kg + kg_base + (key0 + row) * DIMH) + swz * 16;
        __builtin_amdgcn_global_load_lds((gv_t*)srcK, (lv_t*)kdst, 16, 0, 0);
        const char* srcV = (const char*)(vg + vg_base + (long)row * S_TOT + key0) + swz * 16;
        __builtin_amdgcn_global_load_lds((gv_t*)srcV, (lv_t*)vdst, 16, 0, 0);
    };

    STAGE(0, 0);
    asm volatile("s_waitcnt vmcnt(0)" ::: "memory");
    __syncthreads();

    for (int kt0 = 0; kt0 < S_TOT / 64; ++kt0) {
        const int cur = kt0 & 1;
        if (kt0 + 1 < S_TOT / 64) STAGE(cur ^ 1, (long)(kt0 + 1) * 64);

        const char* kb_ = (const char*)(&kbuf[cur][0]);
        const char* vb_ = (const char*)(&vbuf[cur][0]);

        // --- S^T = K Q^T (lane: q=l15, key = kb*16 + g*4 + r) ---
        f32x4 sacc[4];
        __builtin_amdgcn_s_setprio(1);
        #pragma unroll
        for (int kb = 0; kb < 4; ++kb) {
            const int krow = kb * 16 + l15, ks = krow & 7;
            const bf16x8 kf0 = *(const bf16x8*)(kb_ + krow * 128 + ((g ^ ks) << 4));
            const bf16x8 kf1 = *(const bf16x8*)(kb_ + krow * 128 + (((4 + g) ^ ks) << 4));
            sacc[kb] = (f32x4){0.f, 0.f, 0.f, 0.f};
            sacc[kb] = __builtin_amdgcn_mfma_f32_16x16x32_bf16(kf0, qf0, sacc[kb], 0, 0, 0);
            sacc[kb] = __builtin_amdgcn_mfma_f32_16x16x32_bf16(kf1, qf1, sacc[kb], 0, 0, 0);
        }
        __builtin_amdgcn_s_setprio(0);

        // --- per-lane max, vote, rare full reduce + rescale ---
        float tmax = fmaxf(fmaxf(sacc[0][0], sacc[0][1]), fmaxf(sacc[0][2], sacc[0][3]));
        #pragma unroll
        for (int kb = 1; kb < 4; ++kb)
            tmax = fmaxf(tmax, fmaxf(fmaxf(sacc[kb][0], sacc[kb][1]),
                                     fmaxf(sacc[kb][2], sacc[kb][3])));

        if (__any(tmax > mrun + 8.0f)) {
            float tm = fmaxf(tmax, __shfl_xor(tmax, 16, 64));
            tm = fmaxf(tm, __shfl_xor(tm, 32, 64));
            const float mn = fmaxf(mrun, tm);
            const float al = exp2_fast(mrun - mn);
            lrun *= al;
            #pragma unroll
            for (int r = 0; r < 4; ++r) {
                const float alg = __shfl(al, g * 4 + r, 64);
                #pragma unroll
                for (int f = 0; f < 4; ++f) oacc[f][r] *= alg;
            }
            mrun = mn;
        }

        // --- exp + pack P in registers (keys 16kb+4g+{0..3} -> pw.u[2kb..]) ---
        union { unsigned u[8]; bf16x8 v[2]; } pw;
        #pragma unroll
        for (int kb = 0; kb < 4; ++kb) {
            const float p0 = exp2_fast(sacc[kb][0] - mrun);
            const float p1 = exp2_fast(sacc[kb][1] - mrun);
            const float p2 = exp2_fast(sacc[kb][2] - mrun);
            const float p3 = exp2_fast(sacc[kb][3] - mrun);
            lrun += (p0 + p1) + (p2 + p3);
            pw.u[kb * 2]     = cvt_pk_bf16(p0, p1);
            pw.u[kb * 2 + 1] = cvt_pk_bf16(p2, p3);
        }

        // --- O += P V (P = register rename; V keys pre-permuted in global) ---
        __builtin_amdgcn_s_setprio(1);
        #pragma unroll
        for (int ks = 0; ks < 2; ++ks) {
            #pragma unroll
            for (int f = 0; f < 4; ++f) {
                const int vrow = f * 16 + l15;
                const bf16x8 vf = *(const bf16x8*)(vb_ + vrow * 128
                                    + (((ks * 4 + g) ^ (vrow & 7)) << 4));
                oacc[f] = __builtin_amdgcn_mfma_f32_16x16x32_bf16(pw.v[ks], vf, oacc[f], 0, 0, 0);
            }
        }
        __builtin_amdgcn_s_setprio(0);

        asm volatile("s_waitcnt vmcnt(0)" ::: "memory");
        __syncthreads();
    }

    // epilogue: reduce lrun across the 4 lanes of each q, then normalize
    lrun += __shfl_xor(lrun, 16, 64);
    lrun += __shfl_xor(lrun, 32, 64);
    #pragma unroll
    for (int r = 0; r < 4; ++r) {
        const float inv = 1.0f / __shfl(lrun, g * 4 + r, 64);
        const long srow = (long)b * S_TOT + qrow0 + g * 4 + r;
        #pragma unroll
        for (int f = 0; f < 4; ++f)
            aout[srow * HID + h * 64 + f * 16 + l15] = f2bf(oacc[f][r] * inv);
    }
}

// ---------------------------------------------------------------------------
extern "C" void kernel_launch(void* const* d_in, const int* in_sizes, int n_in,
                              void* d_out, int out_size, void* d_ws, size_t ws_size,
                              hipStream_t stream) {
    const float* x     = (const float*)d_in[0];
    const float* w_qkv = (const float*)d_in[1];
    const float* w_out = (const float*)d_in[2];
    const float* b_out = (const float*)d_in[3];
    float* out = (float*)d_out;

    const long PERQKV = (long)2 * NHEAD * S_TOT * DIMH;
    ushort* qws = (ushort*)d_ws;
    ushort* kws = qws + PERQKV;
    ushort* vws = kws + PERQKV;
    ushort* xt  = vws + PERQKV;
    ushort* wqb = xt + (long)2 * S_TOT * CIN;
    ushort* wob = wqb + (long)3 * HID * CIN;
    ushort* awb = wob + (long)CIN * HID;

    cast_f32_bf16<<<dim3((3 * HID * CIN / 4 + 255) / 256), 256, 0, stream>>>(
        w_qkv, wqb, (long)3 * HID * CIN);
    cast_f32_bf16<<<dim3((CIN * HID / 4 + 255) / 256), 256, 0, stream>>>(
        w_out, wob, (long)CIN * HID);
    transpose_cast_x<<<dim3(S_TOT / 64, CIN / 64, 2), 256, 0, stream>>>(x, xt);

    gemm_mfma_kernel<0><<<dim3(1024 / 128, S_TOT / 128, 2), 256, 0, stream>>>(
        xt, wqb, qws, nullptr, CIN, (long)S_TOT * CIN, 0L);
    gemm_mfma_kernel<1><<<dim3(S_TOT / 128, 512 / 128, 2), 256, 0, stream>>>(
        wqb + (long)1024 * CIN, xt, vws, nullptr, CIN, 0L, (long)S_TOT * CIN);

    attn_mfma_kernel<<<dim3(S_TOT / 128, NHEAD, 2), 512, 0, stream>>>(qws, kws, vws, awb);

    gemm_mfma_kernel<2><<<dim3(S_TOT / 128, CIN / 128, 2), 256, 0, stream>>>(
        wob, awb, out, b_out, HID, 0L, (long)S_TOT * HID);
}